// Round 1
// baseline (331.796 us; speedup 1.0000x reference)
//
#include <hip/hip_runtime.h>

// RoleSensitiveEmbedding: out[t,:] = W_{role[t]} @ emb[ids[t],:]
// M=16384 tokens, D=1024. Partition tokens by role -> one bf16 MFMA GEMM per
// region (half the FLOPs of compute-both-and-select).

#define M_TOK   16384
#define DIM     1024
#define MT_ROWS 128
#define NTILES  130                 // ceil(n0/128)+ceil(n1/128) <= 130
#define XROWS   (NTILES * MT_ROWS)  // 16640
#define BK      64

typedef __attribute__((ext_vector_type(8))) short short8;
typedef __attribute__((ext_vector_type(4))) float f32x4;

// ---- workspace layout (bytes) ----
// cnt:  2 ints @ 0
// perm: XROWS ints @ 256
// Wb:   2*1024*1024 bf16 @ 66816
// X:    XROWS*1024 bf16 @ 4261120
// total ~38.3 MB
#define OFF_PERM 256
#define OFF_WB   66816
#define OFF_X    4261120

static __device__ __forceinline__ unsigned short f2bf(float f) {
    unsigned int u = __float_as_uint(f);
    u += 0x7fffu + ((u >> 16) & 1u);   // round-to-nearest-even
    return (unsigned short)(u >> 16);
}

__global__ void k_init(int* perm, int* cnt) {
    int i = blockIdx.x * 256 + threadIdx.x;
    if (i < 2) cnt[i] = 0;
    if (i < XROWS) perm[i] = -1;
}

__global__ void k_perm(const int* __restrict__ role, int* perm, int* cnt) {
    int t = blockIdx.x * 256 + threadIdx.x;   // 0..16383
    int row;
    if (role[t] == 1) { int s = atomicAdd(&cnt[1], 1); row = XROWS - 1 - s; }
    else              { int s = atomicAdd(&cnt[0], 1); row = s; }
    perm[row] = t;
}

// one block per staged row: gather emb row, convert to bf16
__global__ void k_gather(const int* __restrict__ ids, const int* __restrict__ perm,
                         const float* __restrict__ emb, unsigned short* __restrict__ X) {
    int row = blockIdx.x;
    int t = threadIdx.x;
    int p = perm[row];
    ushort4 v = make_ushort4(0, 0, 0, 0);
    if (p >= 0) {
        int id = ids[p];
        float4 f = *(const float4*)(emb + (size_t)id * DIM + t * 4);
        v.x = f2bf(f.x); v.y = f2bf(f.y); v.z = f2bf(f.z); v.w = f2bf(f.w);
    }
    *(ushort4*)(X + (size_t)row * DIM + t * 4) = v;
}

__global__ void k_wconv(const float* __restrict__ W0, const float* __restrict__ W1,
                        unsigned short* __restrict__ Wb) {
    int gid = blockIdx.x * 256 + threadIdx.x;
    int idx = gid * 4;   // 0 .. 2*1048576-4
    const float* src = (idx < 1048576) ? (W0 + idx) : (W1 + (idx - 1048576));
    float4 f = *(const float4*)src;
    ushort4 v = make_ushort4(f2bf(f.x), f2bf(f.y), f2bf(f.z), f2bf(f.w));
    *(ushort4*)(Wb + idx) = v;
}

// 128x128 tile GEMM, C = A * B^T: A = X[XROWS,1024] bf16, B^T = W_e[1024,1024] bf16.
// LDS staged via global_load_lds width=16 with XOR swizzle on the global-gather
// side (kc' = kc ^ (row&7)) so ds_read_b128 fragment reads are ~conflict-free.
__global__ __launch_bounds__(256, 2)
void k_gemm(const unsigned short* __restrict__ Xu, const unsigned short* __restrict__ Wbu,
            const int* __restrict__ perm, const int* __restrict__ cnt,
            float* __restrict__ out) {
    __shared__ short As[MT_ROWS * BK];
    __shared__ short Bs[MT_ROWS * BK];

    // XCD swizzle: f%8 == mt%8 -> all 8 n-tiles of an m-tile land on one XCD
    int f  = blockIdx.x;
    int mt = ((f >> 6) << 3) | (f & 7);
    int nt = (f >> 3) & 7;
    if (mt >= NTILES) return;

    int n0 = cnt[0], n1 = cnt[1];
    int T0 = (n0 + 127) >> 7, T1 = (n1 + 127) >> 7;
    int e;
    if (mt < T0)                e = 0;      // region0 tiles: role 0
    else if (mt >= NTILES - T1) e = 1;      // region1 tiles (top of buffer): role 1
    else return;                            // gap tile

    const short* Ag = (const short*)Xu + (size_t)mt * MT_ROWS * DIM;
    const short* Bg = (const short*)Wbu + (size_t)e * DIM * DIM + (size_t)nt * MT_ROWS * DIM;

    int tid  = threadIdx.x;
    int lane = tid & 63;
    int w    = tid >> 6;         // wave 0..3
    int wm   = w & 1, wn = w >> 1;
    int quad = lane >> 4, lq = lane & 15;

    f32x4 acc[4][4] = {};

    for (int k0 = 0; k0 < DIM; k0 += BK) {
#pragma unroll
        for (int i = 0; i < 4; ++i) {
            int q   = w * 4 + i;          // wave-uniform issue id 0..15
            int s   = q * 64 + lane;      // 16B slot index in tile
            int row = s >> 3;
            int kc  = (s & 7) ^ (row & 7);   // swizzled source k-chunk
            const short* ga = Ag + row * DIM + k0 + kc * 8;
            const short* gb = Bg + row * DIM + k0 + kc * 8;
            __builtin_amdgcn_global_load_lds(
                (const __attribute__((address_space(1))) unsigned int*)ga,
                (__attribute__((address_space(3))) unsigned int*)(&As[q * 512 + lane * 8]),
                16, 0, 0);
            __builtin_amdgcn_global_load_lds(
                (const __attribute__((address_space(1))) unsigned int*)gb,
                (__attribute__((address_space(3))) unsigned int*)(&Bs[q * 512 + lane * 8]),
                16, 0, 0);
        }
        __syncthreads();

#pragma unroll
        for (int s = 0; s < 2; ++s) {
            short8 av[4], bv[4];
            int s4q = s * 4 + quad;
#pragma unroll
            for (int i = 0; i < 4; ++i) {
                int ra = wm * 64 + i * 16 + lq;
                av[i] = *(const short8*)&As[(ra * 8 + (s4q ^ (ra & 7))) * 8];
                int rb = wn * 64 + i * 16 + lq;
                bv[i] = *(const short8*)&Bs[(rb * 8 + (s4q ^ (rb & 7))) * 8];
            }
#pragma unroll
            for (int i = 0; i < 4; ++i)
#pragma unroll
                for (int j = 0; j < 4; ++j)
                    acc[i][j] = __builtin_amdgcn_mfma_f32_16x16x32_bf16(
                        av[i], bv[j], acc[i][j], 0, 0, 0);
        }
        __syncthreads();
    }

    // epilogue: scatter rows to out[token,:]; C/D map: m = quad*4+reg, n = lq
    int colbase = nt * 128 + wn * 64 + lq;
#pragma unroll
    for (int i = 0; i < 4; ++i) {
#pragma unroll
        for (int r = 0; r < 4; ++r) {
            int mrow  = mt * MT_ROWS + wm * 64 + i * 16 + quad * 4 + r;
            int token = perm[mrow];
            if (token < 0) continue;
            float* o = out + (size_t)token * DIM + colbase;
#pragma unroll
            for (int j = 0; j < 4; ++j)
                o[j * 16] = acc[i][j][r];
        }
    }
}

extern "C" void kernel_launch(void* const* d_in, const int* in_sizes, int n_in,
                              void* d_out, int out_size, void* d_ws, size_t ws_size,
                              hipStream_t stream) {
    const int*   ids  = (const int*)d_in[0];
    const int*   role = (const int*)d_in[1];
    const float* emb  = (const float*)d_in[2];
    const float* W0   = (const float*)d_in[3];
    const float* W1   = (const float*)d_in[4];
    float*       out  = (float*)d_out;

    char* ws = (char*)d_ws;
    int* cnt  = (int*)ws;
    int* perm = (int*)(ws + OFF_PERM);
    unsigned short* Wb = (unsigned short*)(ws + OFF_WB);
    unsigned short* X  = (unsigned short*)(ws + OFF_X);

    k_init  <<<(XROWS + 255) / 256, 256, 0, stream>>>(perm, cnt);
    k_perm  <<<M_TOK / 256,        256, 0, stream>>>(role, perm, cnt);
    k_gather<<<XROWS,              256, 0, stream>>>(ids, perm, emb, X);
    k_wconv <<<2 * 1048576 / 1024, 256, 0, stream>>>(W0, W1, Wb);
    k_gemm  <<<1088,               256, 0, stream>>>(X, Wb, perm, cnt, out);
}